// Round 15
// baseline (426.616 us; speedup 1.0000x reference)
//
#include <hip/hip_runtime.h>
#include <hip/hip_bf16.h>
#include <cstdint>
#include <cstddef>

typedef __bf16 bf16_t;
typedef __bf16 bf16x8 __attribute__((ext_vector_type(8)));
typedef float f32x4 __attribute__((ext_vector_type(4)));

#define MFMA16(a, b, c) __builtin_amdgcn_mfma_f32_16x16x32_bf16((a), (b), (c), 0, 0, 0)

__device__ __forceinline__ void gload_lds16(const void* g, void* l) {
  __builtin_amdgcn_global_load_lds((__attribute__((address_space(1))) void*)(g),
                                   (__attribute__((address_space(3))) void*)(l),
                                   16, 0, 0);
}

__device__ __forceinline__ uint32_t pkbf(float lo, float hi) {
  union { bf16_t h[2]; uint32_t u; } u2;
  u2.h[0] = (bf16_t)lo; u2.h[1] = (bf16_t)hi;
  return u2.u;
}

// ---------------------------------------------------------------- cvt x fp32->bf16
__global__ __launch_bounds__(256) void cvt_f32_to_bf16(const float* __restrict__ in,
                                                       bf16_t* __restrict__ out) {
  size_t i = ((size_t)blockIdx.x * 256 + threadIdx.x) * 4;
  float4 v = *(const float4*)(in + i);
  bf16_t o[4] = {(bf16_t)v.x, (bf16_t)v.y, (bf16_t)v.z, (bf16_t)v.w};
  *(uint2*)(out + i) = *(uint2*)o;
}

// ---------------------------------------------------------------- all 8 weight transposes, one dispatch
__global__ __launch_bounds__(256) void transpose_all(
    const float* __restrict__ s0, const float* __restrict__ s1,
    const float* __restrict__ s2, const float* __restrict__ s3,
    const float* __restrict__ s4, const float* __restrict__ s5,
    const float* __restrict__ s6, const float* __restrict__ s7,
    bf16_t* __restrict__ t0, bf16_t* __restrict__ t1, bf16_t* __restrict__ t2,
    bf16_t* __restrict__ t3, bf16_t* __restrict__ t4, bf16_t* __restrict__ t5,
    bf16_t* __restrict__ t6, bf16_t* __restrict__ t7) {
  __shared__ bf16_t tile[32][33];
  const int lid = blockIdx.x;
  const float* src; bf16_t* dst; int R, C, bx, by;
  if (lid < 1536)       { src=s0; dst=t0; R=2048; C=768;  int lo=lid;        bx=lo%24; by=lo/24; }
  else if (lid < 2560)  { src=s1; dst=t1; R=2048; C=512;  int lo=lid-1536;   bx=lo%16; by=lo/16; }
  else if (lid < 4608)  { src=s2; dst=t2; R=2048; C=1024; int lo=lid-2560;   bx=lo%32; by=lo/32; }
  else if (lid < 6656)  { src=s3; dst=t3; R=2048; C=1024; int lo=lid-4608;   bx=lo%32; by=lo/32; }
  else if (lid < 8192)  { src=s4; dst=t4; R=768;  C=2048; int lo=lid-6656;   bx=lo%64; by=lo/64; }
  else if (lid < 9216)  { src=s5; dst=t5; R=512;  C=2048; int lo=lid-8192;   bx=lo%64; by=lo/64; }
  else if (lid < 10752) { src=s6; dst=t6; R=512;  C=3072; int lo=lid-9216;   bx=lo%96; by=lo/96; }
  else                  { src=s7; dst=t7; R=3072; C=2048; int lo=lid-10752;  bx=lo%64; by=lo/64; }
  const int c0 = bx * 32, r0 = by * 32;
  const int tx = threadIdx.x, ty = threadIdx.y;
#pragma unroll
  for (int s = 0; s < 4; s++) {
    int r = ty + s * 8;
    tile[r][tx] = (bf16_t)src[(size_t)(r0 + r) * C + c0 + tx];
  }
  __syncthreads();
#pragma unroll
  for (int s = 0; s < 4; s++) {
    int r = ty + s * 8;
    dst[(size_t)(c0 + r) * R + r0 + tx] = tile[tx][r];
  }
}

// ---------------------------------------------------------------- GEMM: C = A(M,lda)[:, :K] * Bt(N,K)^T
// 128x128 tile, BK=64, 512 thr / 8 waves, per-wave 32x64 (2x4 frags). Double-buffered
// (64KB LDS -> 2 blocks/CU), counted vmcnt(4) + raw s_barrier, unroll-2 static buffers.
// (R13-proven config.) MODE 4 applies RoPE in-register to cols >= 1280.
template <int MODE>
__global__ __launch_bounds__(512, 4) void gemm128(const bf16_t* __restrict__ A, int lda,
                                                  const bf16_t* __restrict__ Bt,
                                                  void* __restrict__ C0, void* __restrict__ C1,
                                                  void* __restrict__ C2, int K, int ldc) {
  __shared__ __align__(16) bf16_t sA0[128 * 64];
  __shared__ __align__(16) bf16_t sB0[128 * 64];
  __shared__ __align__(16) bf16_t sA1[128 * 64];
  __shared__ __align__(16) bf16_t sB1[128 * 64];
  const int tid = threadIdx.x;
  const int l = tid & 63, w = tid >> 6;
  const int l15 = l & 15, l4 = (l >> 4) & 3;
  const int wr = w >> 1, wc = w & 1;
  const int m0 = blockIdx.y * 128, n0 = blockIdx.x * 128;
  const int nt = K >> 6;

  f32x4 acc[2][4] = {};

#define STAGEG(SA, SB, KT)                                                          \
  {                                                                                 \
    const int kts = (KT) * 64;                                                      \
    _Pragma("unroll")                                                               \
    for (int r = 0; r < 2; r++) {                                                   \
      int i = r * 512 + tid;                                                        \
      int row = i >> 3, cl = i & 7;                                                 \
      int cg = cl ^ (row & 7);                                                      \
      gload_lds16(A + (size_t)(m0 + row) * lda + kts + cg * 8,                      \
                  (char*)(SA) + (size_t)(r * 512 + w * 64) * 16);                   \
    }                                                                               \
    _Pragma("unroll")                                                               \
    for (int r = 0; r < 2; r++) {                                                   \
      int i = r * 512 + tid;                                                        \
      int row = i >> 3, cl = i & 7;                                                 \
      int cg = cl ^ (row & 7);                                                      \
      gload_lds16(Bt + (size_t)(n0 + row) * K + kts + cg * 8,                       \
                  (char*)(SB) + (size_t)(r * 512 + w * 64) * 16);                   \
    }                                                                               \
  }

#define GCOMPUTE(SA, SB)                                                            \
  {                                                                                 \
    _Pragma("unroll")                                                               \
    for (int ks = 0; ks < 2; ks++) {                                                \
      bf16x8 af[2], bfr[4];                                                         \
      _Pragma("unroll")                                                             \
      for (int mf = 0; mf < 2; mf++) {                                              \
        int row = wr * 32 + mf * 16 + l15;                                          \
        int cl = (ks * 4 + l4) ^ (row & 7);                                         \
        af[mf] = *(const bf16x8*)((SA) + row * 64 + cl * 8);                        \
      }                                                                             \
      _Pragma("unroll")                                                             \
      for (int nf = 0; nf < 4; nf++) {                                              \
        int row = wc * 64 + nf * 16 + l15;                                          \
        int cl = (ks * 4 + l4) ^ (row & 7);                                         \
        bfr[nf] = *(const bf16x8*)((SB) + row * 64 + cl * 8);                       \
      }                                                                             \
      __builtin_amdgcn_s_setprio(1);                                                \
      _Pragma("unroll")                                                             \
      for (int mf = 0; mf < 2; mf++)                                                \
        _Pragma("unroll")                                                           \
        for (int nf = 0; nf < 4; nf++)                                              \
          acc[mf][nf] = MFMA16(af[mf], bfr[nf], acc[mf][nf]);                       \
      __builtin_amdgcn_s_setprio(0);                                                \
    }                                                                               \
  }

  STAGEG(sA0, sB0, 0)
  for (int t = 0; t < nt; t += 2) {
    STAGEG(sA1, sB1, t + 1)
    asm volatile("s_waitcnt vmcnt(4)\n\ts_barrier" ::: "memory");
    GCOMPUTE(sA0, sB0)
    asm volatile("s_barrier" ::: "memory");
    if (t + 2 < nt) {
      STAGEG(sA0, sB0, t + 2)
      asm volatile("s_waitcnt vmcnt(4)\n\ts_barrier" ::: "memory");
    } else {
      asm volatile("s_waitcnt vmcnt(0)\n\ts_barrier" ::: "memory");
    }
    GCOMPUTE(sA1, sB1)
    asm volatile("s_barrier" ::: "memory");
  }
#undef STAGEG
#undef GCOMPUTE

  // RoPE applied in-register for fuse1's rope region (cols >= 1280).
  if constexpr (MODE == 4) {
    if (n0 + wc * 64 >= 1280) {
      float inv0 = expf(-(float)l15 * 0.28782313662425574f);
      float inv1 = expf(-(float)(l15 + 16) * 0.28782313662425574f);
#pragma unroll
      for (int mf = 0; mf < 2; mf++)
#pragma unroll
        for (int r = 0; r < 4; r++) {
          int m = m0 + wr * 32 + mf * 16 + l4 * 4 + r;
          float tt = (float)(m & 2047);
          float c0v, s0v, c1v, s1v;
          sincosf(tt * inv0, &s0v, &c0v);
          sincosf(tt * inv1, &s1v, &c1v);
          float x1a = acc[mf][0][r], x2a = acc[mf][2][r];
          acc[mf][0][r] = x1a * c0v - x2a * s0v;
          acc[mf][2][r] = x1a * s0v + x2a * c0v;
          float x1b = acc[mf][1][r], x2b = acc[mf][3][r];
          acc[mf][1][r] = x1b * c1v - x2b * s1v;
          acc[mf][3][r] = x1b * s1v + x2b * c1v;
        }
    }
  }

#pragma unroll
  for (int mf = 0; mf < 2; mf++)
#pragma unroll
    for (int nf = 0; nf < 4; nf++) {
      const int mbase = m0 + wr * 32 + mf * 16 + l4 * 4;
      const int n = n0 + wc * 64 + nf * 16 + l15;
      if constexpr (MODE == 1) {
#pragma unroll
        for (int r = 0; r < 4; r++)
          ((float*)C0)[(size_t)(mbase + r) * ldc + n] = acc[mf][nf][r];
      } else if constexpr (MODE == 2) {
#pragma unroll
        for (int r = 0; r < 4; r++)
          ((bf16_t*)C0)[(size_t)(mbase + r) * 3072 + (n >> 7) * 192 + (n & 127)] =
              (bf16_t)acc[mf][nf][r];
      } else if constexpr (MODE == 4) {
        if (n < 1280) {
#pragma unroll
          for (int r = 0; r < 4; r++)
            ((bf16_t*)C0)[(size_t)(mbase + r) * 1280 + n] = (bf16_t)acc[mf][nf][r];
        } else if (n < 2304) {
          int nn = n - 1280;
#pragma unroll
          for (int r = 0; r < 4; r++)
            ((bf16_t*)C1)[(size_t)(mbase + r) * 3072 + (nn >> 6) * 192 + 128 + (nn & 63)] =
                (bf16_t)acc[mf][nf][r];
        } else {
          int nn = n - 2304;
#pragma unroll
          for (int r = 0; r < 4; r++)
            ((bf16_t*)C2)[(size_t)(mbase + r) * 3072 + (nn >> 6) * 192 + 128 + (nn & 63)] =
                (bf16_t)acc[mf][nf][r];
        }
      } else {  // MODE 5
        if (n < 2048) {
#pragma unroll
          for (int r = 0; r < 4; r++)
            ((bf16_t*)C0)[(size_t)(mbase + r) * 3072 + (n >> 7) * 192 + (n & 127)] =
                (bf16_t)acc[mf][nf][r];
        } else {
          int nn = n - 2048;            // 0..3071
          int hh = nn / 192, dd = nn - hh * 192;
          int bb = mbase >> 11, tt = mbase & 2047;
          bf16_t pk4[4] = {(bf16_t)acc[mf][nf][0], (bf16_t)acc[mf][nf][1],
                           (bf16_t)acc[mf][nf][2], (bf16_t)acc[mf][nf][3]};
          *(uint2*)((bf16_t*)C1 + ((size_t)(bb * 16 + hh) * 192 + dd) * 2048 + tt) =
              *(uint2*)pk4;
        }
      }
    }
}

// ---------------------------------------------------------------- flash attention (causal)
// R13 structure; softmax reworked to raw-domain masking + single-fma exp2:
// track running max in RAW S domain, p = exp2(fma(s, qs, -mrow*qs)) where
// qs = (1/sqrt(192))*log2(e). 2 VALU ops/elem instead of 4.
__global__ __launch_bounds__(512, 2) void attn_kernel(const bf16_t* __restrict__ q,
                                                      const bf16_t* __restrict__ kbuf,
                                                      const bf16_t* __restrict__ vt,
                                                      bf16_t* __restrict__ ao) {
  __shared__ __align__(16) bf16_t sK0[64][192];  // perm-24 swizzle
  __shared__ __align__(16) bf16_t sK1[64][192];
  __shared__ __align__(16) bf16_t sV0[192][64];  // xor-8 chunk swizzle
  __shared__ __align__(16) bf16_t sV1[192][64];

  const int tid = threadIdx.x, l = tid & 63, w = tid >> 6;
  const int l15 = l & 15, l4 = (l >> 4) & 3;
  const int bh = blockIdx.x & 31;            // same-bh blocks share an XCD (i%8 preserved)
  const int c = blockIdx.x >> 5;             // pair index 0..7
  const int b = bh >> 4, h = bh & 15;
  const int ca = c, cb = 15 - c;             // 128-row chunks
  const int ra = ca * 128 + w * 16;
  const int rb = cb * 128 + w * 16;
  const int tga = 2 * ca + (w >> 2);         // diag k-tile for this wave's chunk-a rows
  const int tgb = 2 * cb + (w >> 2);

  const bf16_t* qp = q + (size_t)b * 2048 * 3072 + h * 192;
  const bf16_t* kp = kbuf + (size_t)b * 2048 * 3072 + h * 192;
  const bf16_t* vp = vt + (size_t)bh * 192 * 2048;

  bf16x8 qf[2][6];
#pragma unroll
  for (int kd = 0; kd < 6; kd++) {
    qf[0][kd] = *(const bf16x8*)(qp + (size_t)(ra + l15) * 3072 + kd * 32 + l4 * 8);
    qf[1][kd] = *(const bf16x8*)(qp + (size_t)(rb + l15) * 3072 + kd * 32 + l4 * 8);
  }

  f32x4 o[2][12] = {};
  float mrow[2] = {-__builtin_inff(), -__builtin_inff()};
  float lrow[2] = {0.0f, 0.0f};

  const float qs = 0.10412766786f;           // (1/sqrt(192)) * log2(e)
  const float THR = 97.0f;                   // defer-max threshold, raw-S domain (~7 nats)
  const int nkt = 2 * cb + 2;                // always even
  const int src0 = l15 + ((l4 & 1) << 5);
  const int src1 = src0 + 16;
  const bool hibank = (l4 & 2) != 0;

#define STAGE(SK, SV, KT)                                                           \
  {                                                                                 \
    const int k0s = (KT) * 64;                                                      \
    _Pragma("unroll")                                                               \
    for (int r = 0; r < 3; r++) {                                                   \
      int i = r * 512 + tid;                                                        \
      int row = i / 24, cc = i % 24;                                                \
      int g = cc - (row & 7) * 3;                                                   \
      if (g < 0) g += 24;                                                           \
      gload_lds16(kp + (size_t)(k0s + row) * 3072 + g * 8,                          \
                  (char*)&SK[0][0] + (size_t)(r * 512 + w * 64) * 16);              \
    }                                                                               \
    _Pragma("unroll")                                                               \
    for (int r = 0; r < 3; r++) {                                                   \
      int i = r * 512 + tid;                                                        \
      int d = i >> 3, cc = i & 7;                                                   \
      gload_lds16(vp + (size_t)d * 2048 + k0s + (cc ^ (d & 7)) * 8,                 \
                  (char*)&SV[0][0] + (size_t)(r * 512 + w * 64) * 16);              \
    }                                                                               \
  }

#define SOFTMAX_CHUNK(c, rbase, tg)                                                    \
    {                                                                                  \
      const bool diag = (kt == (tg));                                                  \
      if (diag) {                                                                      \
        _Pragma("unroll")                                                              \
        for (int nf = 0; nf < 4; nf++)                                                 \
          _Pragma("unroll")                                                            \
          for (int r = 0; r < 4; r++) {                                                \
            int ktok = k0 + nf * 16 + l4 * 4 + r;                                      \
            if (ktok > (rbase) + l15) s[c][nf][r] = -__builtin_inff();                 \
          }                                                                            \
      }                                                                                \
      float m_in = s[c][0][0];                                                         \
      _Pragma("unroll")                                                                \
      for (int nf = 0; nf < 4; nf++)                                                   \
        _Pragma("unroll")                                                              \
        for (int r = 0; r < 4; r++)                                                    \
          if (nf | r) m_in = fmaxf(m_in, s[c][nf][r]);                                 \
      m_in = fmaxf(m_in, __shfl_xor(m_in, 16));                                        \
      m_in = fmaxf(m_in, __shfl_xor(m_in, 32));                                        \
      if (!__all(m_in - mrow[c] <= THR)) {                                             \
        float mn = fmaxf(mrow[c], m_in);                                               \
        float alpha = __builtin_exp2f((mrow[c] - mn) * qs);                            \
        mrow[c] = mn;                                                                  \
        lrow[c] *= alpha;                                                              \
        f32x4 av;                                                                      \
        _Pragma("unroll")                                                              \
        for (int r = 0; r < 4; r++) av[r] = __shfl(alpha, l4 * 4 + r);                 \
        _Pragma("unroll")                                                              \
        for (int nf2 = 0; nf2 < 12; nf2++) o[c][nf2] *= av;                            \
      }                                                                                \
      const float mq = mrow[c] * qs;                                                   \
      float rs = 0.0f;                                                                 \
      _Pragma("unroll")                                                                \
      for (int nf = 0; nf < 4; nf++)                                                   \
        _Pragma("unroll")                                                              \
        for (int r = 0; r < 4; r++) {                                                  \
          float pv = __builtin_exp2f(__builtin_fmaf(s[c][nf][r], qs, -mq));            \
          s[c][nf][r] = pv;                                                            \
          rs += pv;                                                                    \
        }                                                                              \
      rs += __shfl_xor(rs, 16);                                                        \
      rs += __shfl_xor(rs, 32);                                                        \
      lrow[c] += rs;                                                                   \
      uint32_t wq[8];                                                                  \
      _Pragma("unroll")                                                                \
      for (int nf = 0; nf < 4; nf++) {                                                 \
        wq[nf * 2 + 0] = pkbf(s[c][nf][0], s[c][nf][1]);                               \
        wq[nf * 2 + 1] = pkbf(s[c][nf][2], s[c][nf][3]);                               \
      }                                                                                \
      _Pragma("unroll")                                                                \
      for (int ks = 0; ks < 2; ks++) {                                                 \
        uint32_t A0 = __shfl(wq[(2 * ks) * 2 + 0], src0);                              \
        uint32_t A1 = __shfl(wq[(2 * ks) * 2 + 1], src0);                              \
        uint32_t B0 = __shfl(wq[(2 * ks + 1) * 2 + 0], src0);                          \
        uint32_t B1 = __shfl(wq[(2 * ks + 1) * 2 + 1], src0);                          \
        uint32_t C0w = __shfl(wq[(2 * ks) * 2 + 0], src1);                             \
        uint32_t C1w = __shfl(wq[(2 * ks) * 2 + 1], src1);                             \
        uint32_t D0 = __shfl(wq[(2 * ks + 1) * 2 + 0], src1);                          \
        uint32_t D1 = __shfl(wq[(2 * ks + 1) * 2 + 1], src1);                          \
        union { uint32_t u[4]; bf16x8 v; } fr;                                         \
        fr.u[0] = hibank ? B0 : A0;                                                    \
        fr.u[1] = hibank ? B1 : A1;                                                    \
        fr.u[2] = hibank ? D0 : C0w;                                                   \
        fr.u[3] = hibank ? D1 : C1w;                                                   \
        pa[c][ks] = fr.v;                                                              \
      }                                                                                \
    }

#define TILE_BODY(SK, SV, KT)                                                          \
  {                                                                                    \
    const int kt = (KT);                                                               \
    const int k0 = kt * 64;                                                            \
    const bool act_a = (kt <= tga);                                                    \
    const bool act_b = (kt <= tgb);                                                    \
    f32x4 s[2][4] = {};                                                                \
    __builtin_amdgcn_s_setprio(1);                                                     \
    _Pragma("unroll")                                                                  \
    for (int kd = 0; kd < 6; kd++) {                                                   \
      bf16x8 bk[4];                                                                    \
      _Pragma("unroll")                                                                \
      for (int nf = 0; nf < 4; nf++) {                                                 \
        int row = nf * 16 + l15;                                                       \
        int cl = kd * 4 + l4 + (row & 7) * 3;                                          \
        if (cl >= 24) cl -= 24;                                                        \
        bk[nf] = *(const bf16x8*)(&SK[row][cl * 8]);                                   \
      }                                                                                \
      if (act_b) {                                                                     \
        _Pragma("unroll")                                                              \
        for (int nf = 0; nf < 4; nf++)                                                 \
          s[1][nf] = MFMA16(bk[nf], qf[1][kd], s[1][nf]);                              \
      }                                                                                \
      if (act_a) {                                                                     \
        _Pragma("unroll")                                                              \
        for (int nf = 0; nf < 4; nf++)                                                 \
          s[0][nf] = MFMA16(bk[nf], qf[0][kd], s[0][nf]);                              \
      }                                                                                \
    }                                                                                  \
    __builtin_amdgcn_s_setprio(0);                                                     \
    bf16x8 pa[2][2] = {};                                                              \
    if (act_b) SOFTMAX_CHUNK(1, rb, tgb)                                               \
    if (act_a) SOFTMAX_CHUNK(0, ra, tga)                                               \
    __builtin_amdgcn_s_setprio(1);                                                     \
    _Pragma("unroll")                                                                  \
    for (int ks = 0; ks < 2; ks++) {                                                   \
      _Pragma("unroll")                                                                \
      for (int nf2 = 0; nf2 < 12; nf2++) {                                             \
        int d = nf2 * 16 + l15;                                                        \
        int cl = (ks * 4 + l4) ^ (d & 7);                                              \
        bf16x8 vb = *(const bf16x8*)(&SV[d][cl * 8]);                                  \
        if (act_b) o[1][nf2] = MFMA16(pa[1][ks], vb, o[1][nf2]);                       \
        if (act_a) o[0][nf2] = MFMA16(pa[0][ks], vb, o[0][nf2]);                       \
      }                                                                                \
    }                                                                                  \
    __builtin_amdgcn_s_setprio(0);                                                     \
  }

  STAGE(sK0, sV0, 0)
  __syncthreads();  // tile 0 ready

  for (int kt0 = 0; kt0 < nkt; kt0 += 2) {
    STAGE(sK1, sV1, kt0 + 1)
    TILE_BODY(sK0, sV0, kt0)
    __syncthreads();
    if (kt0 + 2 < nkt) STAGE(sK0, sV0, kt0 + 2)
    TILE_BODY(sK1, sV1, kt0 + 1)
    __syncthreads();
  }
#undef STAGE
#undef SOFTMAX_CHUNK
#undef TILE_BODY

  // epilogue: O/l -> ao (b*T+q, h*192+d), both chunks; l lives at lane l15=q
#pragma unroll
  for (int mf = 0; mf < 2; mf++) {
    const int rbase = (mf == 0) ? ra : rb;
#pragma unroll
    for (int r = 0; r < 4; r++) {
      float lv = __shfl(lrow[mf], l4 * 4 + r);
      float inv = 1.0f / lv;
      int qrow = rbase + l4 * 4 + r;
#pragma unroll
      for (int nf2 = 0; nf2 < 12; nf2++) {
        int d = nf2 * 16 + l15;
        ao[(size_t)(b * 2048 + qrow) * 3072 + h * 192 + d] = (bf16_t)(o[mf][nf2][r] * inv);
      }
    }
  }
}

// ----------------------------------------------------------------
extern "C" void kernel_launch(void* const* d_in, const int* in_sizes, int n_in,
                              void* d_out, int out_size, void* d_ws, size_t ws_size,
                              hipStream_t stream) {
  const float* x       = (const float*)d_in[0];
  const float* wq_down = (const float*)d_in[1];
  const float* wq_up   = (const float*)d_in[2];
  const float* wq_rope = (const float*)d_in[3];
  const float* wkv_down= (const float*)d_in[4];
  const float* wk_up   = (const float*)d_in[5];
  const float* wv_up   = (const float*)d_in[6];
  const float* wk_rope = (const float*)d_in[7];
  const float* wo      = (const float*)d_in[8];
  float* out = (float*)d_out;

  char* p = (char*)d_ws;
  auto take = [&](size_t elems) { bf16_t* r = (bf16_t*)p; p += elems * 2; return r; };
  bf16_t* xb    = take(4096ull * 2048);
  bf16_t* fw1   = take(3328ull * 2048);  // [wq_down(768) | wkv_down(512) | wq_rope(1024) | wk_rope(1024)]^T
  bf16_t* wqu_t = take(2048ull * 768);
  bf16_t* fw2   = take(5120ull * 512);   // [wk_up(2048) | wv_up(3072)]^T
  bf16_t* wo_t  = take(2048ull * 3072);
  bf16_t* qkvd  = take(4096ull * 1280);  // [q_down(768) | latent(512)]
  bf16_t* qbuf  = take(4096ull * 3072);
  bf16_t* kbuf  = take(4096ull * 3072);
  bf16_t* ao    = take(4096ull * 3072);
  bf16_t* vt    = take(4096ull * 3072);

  dim3 tb(32, 8);
  cvt_f32_to_bf16<<<8192, 256, 0, stream>>>(x, xb);
  transpose_all<<<16896, tb, 0, stream>>>(
      wq_down, wkv_down, wq_rope, wk_rope, wq_up, wk_up, wv_up, wo,
      fw1, fw1 + 768ull * 2048, fw1 + 1280ull * 2048, fw1 + 2304ull * 2048,
      wqu_t, fw2, fw2 + 2048ull * 512, wo_t);

  gemm128<4><<<dim3(26, 32), 512, 0, stream>>>(xb, 2048, fw1, qkvd, qbuf, kbuf, 2048, 0);
  gemm128<2><<<dim3(16, 32), 512, 0, stream>>>(qkvd, 1280, wqu_t, qbuf, nullptr, nullptr, 768, 0);
  gemm128<5><<<dim3(40, 32), 512, 0, stream>>>(qkvd + 768, 1280, fw2, kbuf, vt, nullptr, 512, 0);

  attn_kernel<<<256, 512, 0, stream>>>(qbuf, kbuf, vt, ao);

  gemm128<1><<<dim3(16, 32), 512, 0, stream>>>(ao, 3072, wo_t, out, nullptr, nullptr, 3072, 2048);
}

// Round 16
// 315.594 us; speedup vs baseline: 1.3518x; 1.3518x over previous
//
#include <hip/hip_runtime.h>
#include <hip/hip_bf16.h>
#include <cstdint>
#include <cstddef>

typedef __bf16 bf16_t;
typedef __bf16 bf16x8 __attribute__((ext_vector_type(8)));
typedef float f32x4 __attribute__((ext_vector_type(4)));

#define MFMA16(a, b, c) __builtin_amdgcn_mfma_f32_16x16x32_bf16((a), (b), (c), 0, 0, 0)

__device__ __forceinline__ void gload_lds16(const void* g, void* l) {
  __builtin_amdgcn_global_load_lds((__attribute__((address_space(1))) void*)(g),
                                   (__attribute__((address_space(3))) void*)(l),
                                   16, 0, 0);
}

__device__ __forceinline__ uint32_t pkbf(float lo, float hi) {
  union { bf16_t h[2]; uint32_t u; } u2;
  u2.h[0] = (bf16_t)lo; u2.h[1] = (bf16_t)hi;
  return u2.u;
}

// ---------------------------------------------------------------- prologue: 8 weight transposes + x cvt, one dispatch
// Blocks [0,16896): fp32 (R,C) -> bf16 (C,R) transposes (prefix-range routed).
// Blocks [16896, 25088): x fp32 -> bf16 copy-convert (4 floats/thread).
__global__ __launch_bounds__(256) void transpose_all(
    const float* __restrict__ s0, const float* __restrict__ s1,
    const float* __restrict__ s2, const float* __restrict__ s3,
    const float* __restrict__ s4, const float* __restrict__ s5,
    const float* __restrict__ s6, const float* __restrict__ s7,
    bf16_t* __restrict__ t0, bf16_t* __restrict__ t1, bf16_t* __restrict__ t2,
    bf16_t* __restrict__ t3, bf16_t* __restrict__ t4, bf16_t* __restrict__ t5,
    bf16_t* __restrict__ t6, bf16_t* __restrict__ t7,
    const float* __restrict__ x, bf16_t* __restrict__ xb) {
  __shared__ bf16_t tile[32][33];
  const int lid = blockIdx.x;
  const int tx = threadIdx.x, ty = threadIdx.y;
  if (lid >= 16896) {
    // cvt region
    int tid = ty * 32 + tx;
    size_t i = ((size_t)(lid - 16896) * 256 + tid) * 4;
    float4 v = *(const float4*)(x + i);
    bf16_t o[4] = {(bf16_t)v.x, (bf16_t)v.y, (bf16_t)v.z, (bf16_t)v.w};
    *(uint2*)(xb + i) = *(uint2*)o;
    return;
  }
  const float* src; bf16_t* dst; int R, C, bx, by;
  if (lid < 1536)       { src=s0; dst=t0; R=2048; C=768;  int lo=lid;        bx=lo%24; by=lo/24; }
  else if (lid < 2560)  { src=s1; dst=t1; R=2048; C=512;  int lo=lid-1536;   bx=lo%16; by=lo/16; }
  else if (lid < 4608)  { src=s2; dst=t2; R=2048; C=1024; int lo=lid-2560;   bx=lo%32; by=lo/32; }
  else if (lid < 6656)  { src=s3; dst=t3; R=2048; C=1024; int lo=lid-4608;   bx=lo%32; by=lo/32; }
  else if (lid < 8192)  { src=s4; dst=t4; R=768;  C=2048; int lo=lid-6656;   bx=lo%64; by=lo/64; }
  else if (lid < 9216)  { src=s5; dst=t5; R=512;  C=2048; int lo=lid-8192;   bx=lo%64; by=lo/64; }
  else if (lid < 10752) { src=s6; dst=t6; R=512;  C=3072; int lo=lid-9216;   bx=lo%96; by=lo/96; }
  else                  { src=s7; dst=t7; R=3072; C=2048; int lo=lid-10752;  bx=lo%64; by=lo/64; }
  const int c0 = bx * 32, r0 = by * 32;
#pragma unroll
  for (int s = 0; s < 4; s++) {
    int r = ty + s * 8;
    tile[r][tx] = (bf16_t)src[(size_t)(r0 + r) * C + c0 + tx];
  }
  __syncthreads();
#pragma unroll
  for (int s = 0; s < 4; s++) {
    int r = ty + s * 8;
    dst[(size_t)(c0 + r) * R + r0 + tx] = tile[tx][r];
  }
}

// ---------------------------------------------------------------- GEMM: C = A(M,lda)[:, :K] * Bt(N,K)^T
// 128x128 tile, BK=64, 512 thr / 8 waves, per-wave 32x64 (2x4 frags). Double-buffered
// (64KB LDS -> 2 blocks/CU), counted vmcnt(4) + raw s_barrier, unroll-2 static buffers.
// (R13-proven config.) MODE 4 applies RoPE in-register to cols >= 1280.
template <int MODE>
__global__ __launch_bounds__(512, 4) void gemm128(const bf16_t* __restrict__ A, int lda,
                                                  const bf16_t* __restrict__ Bt,
                                                  void* __restrict__ C0, void* __restrict__ C1,
                                                  void* __restrict__ C2, int K, int ldc) {
  __shared__ __align__(16) bf16_t sA0[128 * 64];
  __shared__ __align__(16) bf16_t sB0[128 * 64];
  __shared__ __align__(16) bf16_t sA1[128 * 64];
  __shared__ __align__(16) bf16_t sB1[128 * 64];
  const int tid = threadIdx.x;
  const int l = tid & 63, w = tid >> 6;
  const int l15 = l & 15, l4 = (l >> 4) & 3;
  const int wr = w >> 1, wc = w & 1;
  const int m0 = blockIdx.y * 128, n0 = blockIdx.x * 128;
  const int nt = K >> 6;

  f32x4 acc[2][4] = {};

#define STAGEG(SA, SB, KT)                                                          \
  {                                                                                 \
    const int kts = (KT) * 64;                                                      \
    _Pragma("unroll")                                                               \
    for (int r = 0; r < 2; r++) {                                                   \
      int i = r * 512 + tid;                                                        \
      int row = i >> 3, cl = i & 7;                                                 \
      int cg = cl ^ (row & 7);                                                      \
      gload_lds16(A + (size_t)(m0 + row) * lda + kts + cg * 8,                      \
                  (char*)(SA) + (size_t)(r * 512 + w * 64) * 16);                   \
    }                                                                               \
    _Pragma("unroll")                                                               \
    for (int r = 0; r < 2; r++) {                                                   \
      int i = r * 512 + tid;                                                        \
      int row = i >> 3, cl = i & 7;                                                 \
      int cg = cl ^ (row & 7);                                                      \
      gload_lds16(Bt + (size_t)(n0 + row) * K + kts + cg * 8,                       \
                  (char*)(SB) + (size_t)(r * 512 + w * 64) * 16);                   \
    }                                                                               \
  }

#define GCOMPUTE(SA, SB)                                                            \
  {                                                                                 \
    _Pragma("unroll")                                                               \
    for (int ks = 0; ks < 2; ks++) {                                                \
      bf16x8 af[2], bfr[4];                                                         \
      _Pragma("unroll")                                                             \
      for (int mf = 0; mf < 2; mf++) {                                              \
        int row = wr * 32 + mf * 16 + l15;                                          \
        int cl = (ks * 4 + l4) ^ (row & 7);                                         \
        af[mf] = *(const bf16x8*)((SA) + row * 64 + cl * 8);                        \
      }                                                                             \
      _Pragma("unroll")                                                             \
      for (int nf = 0; nf < 4; nf++) {                                              \
        int row = wc * 64 + nf * 16 + l15;                                          \
        int cl = (ks * 4 + l4) ^ (row & 7);                                         \
        bfr[nf] = *(const bf16x8*)((SB) + row * 64 + cl * 8);                       \
      }                                                                             \
      __builtin_amdgcn_s_setprio(1);                                                \
      _Pragma("unroll")                                                             \
      for (int mf = 0; mf < 2; mf++)                                                \
        _Pragma("unroll")                                                           \
        for (int nf = 0; nf < 4; nf++)                                              \
          acc[mf][nf] = MFMA16(af[mf], bfr[nf], acc[mf][nf]);                       \
      __builtin_amdgcn_s_setprio(0);                                                \
    }                                                                               \
  }

  STAGEG(sA0, sB0, 0)
  for (int t = 0; t < nt; t += 2) {
    STAGEG(sA1, sB1, t + 1)
    asm volatile("s_waitcnt vmcnt(4)\n\ts_barrier" ::: "memory");
    GCOMPUTE(sA0, sB0)
    asm volatile("s_barrier" ::: "memory");
    if (t + 2 < nt) {
      STAGEG(sA0, sB0, t + 2)
      asm volatile("s_waitcnt vmcnt(4)\n\ts_barrier" ::: "memory");
    } else {
      asm volatile("s_waitcnt vmcnt(0)\n\ts_barrier" ::: "memory");
    }
    GCOMPUTE(sA1, sB1)
    asm volatile("s_barrier" ::: "memory");
  }
#undef STAGEG
#undef GCOMPUTE

  // RoPE applied in-register for fuse1's rope region (cols >= 1280).
  if constexpr (MODE == 4) {
    if (n0 + wc * 64 >= 1280) {
      float inv0 = expf(-(float)l15 * 0.28782313662425574f);
      float inv1 = expf(-(float)(l15 + 16) * 0.28782313662425574f);
#pragma unroll
      for (int mf = 0; mf < 2; mf++)
#pragma unroll
        for (int r = 0; r < 4; r++) {
          int m = m0 + wr * 32 + mf * 16 + l4 * 4 + r;
          float tt = (float)(m & 2047);
          float c0v, s0v, c1v, s1v;
          sincosf(tt * inv0, &s0v, &c0v);
          sincosf(tt * inv1, &s1v, &c1v);
          float x1a = acc[mf][0][r], x2a = acc[mf][2][r];
          acc[mf][0][r] = x1a * c0v - x2a * s0v;
          acc[mf][2][r] = x1a * s0v + x2a * c0v;
          float x1b = acc[mf][1][r], x2b = acc[mf][3][r];
          acc[mf][1][r] = x1b * c1v - x2b * s1v;
          acc[mf][3][r] = x1b * s1v + x2b * c1v;
        }
    }
  }

#pragma unroll
  for (int mf = 0; mf < 2; mf++)
#pragma unroll
    for (int nf = 0; nf < 4; nf++) {
      const int mbase = m0 + wr * 32 + mf * 16 + l4 * 4;
      const int n = n0 + wc * 64 + nf * 16 + l15;
      if constexpr (MODE == 1) {
#pragma unroll
        for (int r = 0; r < 4; r++)
          ((float*)C0)[(size_t)(mbase + r) * ldc + n] = acc[mf][nf][r];
      } else if constexpr (MODE == 2) {
#pragma unroll
        for (int r = 0; r < 4; r++)
          ((bf16_t*)C0)[(size_t)(mbase + r) * 3072 + (n >> 7) * 192 + (n & 127)] =
              (bf16_t)acc[mf][nf][r];
      } else if constexpr (MODE == 4) {
        if (n < 1280) {
#pragma unroll
          for (int r = 0; r < 4; r++)
            ((bf16_t*)C0)[(size_t)(mbase + r) * 1280 + n] = (bf16_t)acc[mf][nf][r];
        } else if (n < 2304) {
          int nn = n - 1280;
#pragma unroll
          for (int r = 0; r < 4; r++)
            ((bf16_t*)C1)[(size_t)(mbase + r) * 3072 + (nn >> 6) * 192 + 128 + (nn & 63)] =
                (bf16_t)acc[mf][nf][r];
        } else {
          int nn = n - 2304;
#pragma unroll
          for (int r = 0; r < 4; r++)
            ((bf16_t*)C2)[(size_t)(mbase + r) * 3072 + (nn >> 6) * 192 + 128 + (nn & 63)] =
                (bf16_t)acc[mf][nf][r];
        }
      } else {  // MODE 5
        if (n < 2048) {
#pragma unroll
          for (int r = 0; r < 4; r++)
            ((bf16_t*)C0)[(size_t)(mbase + r) * 3072 + (n >> 7) * 192 + (n & 127)] =
                (bf16_t)acc[mf][nf][r];
        } else {
          int nn = n - 2048;            // 0..3071
          int hh = nn / 192, dd = nn - hh * 192;
          int bb = mbase >> 11, tt = mbase & 2047;
          bf16_t pk4[4] = {(bf16_t)acc[mf][nf][0], (bf16_t)acc[mf][nf][1],
                           (bf16_t)acc[mf][nf][2], (bf16_t)acc[mf][nf][3]};
          *(uint2*)((bf16_t*)C1 + ((size_t)(bb * 16 + hh) * 192 + dd) * 2048 + tt) =
              *(uint2*)pk4;
        }
      }
    }
}

// ---------------------------------------------------------------- flash attention (causal)
// R13-exact: 8 waves / 512 threads, pairs (c,31-c) of 128-row chunks; statically
// distinct K/V double buffers in LDS, 2x-unrolled loop, gload_lds prefetch one tile
// ahead, setprio around MFMA clusters, scale-first __expf softmax.
__global__ __launch_bounds__(512, 2) void attn_kernel(const bf16_t* __restrict__ q,
                                                      const bf16_t* __restrict__ kbuf,
                                                      const bf16_t* __restrict__ vt,
                                                      bf16_t* __restrict__ ao) {
  __shared__ __align__(16) bf16_t sK0[64][192];  // perm-24 swizzle
  __shared__ __align__(16) bf16_t sK1[64][192];
  __shared__ __align__(16) bf16_t sV0[192][64];  // xor-8 chunk swizzle
  __shared__ __align__(16) bf16_t sV1[192][64];

  const int tid = threadIdx.x, l = tid & 63, w = tid >> 6;
  const int l15 = l & 15, l4 = (l >> 4) & 3;
  const int bh = blockIdx.x & 31;            // same-bh blocks share an XCD (i%8 preserved)
  const int c = blockIdx.x >> 5;             // pair index 0..7
  const int b = bh >> 4, h = bh & 15;
  const int ca = c, cb = 15 - c;             // 128-row chunks
  const int ra = ca * 128 + w * 16;
  const int rb = cb * 128 + w * 16;
  const int tga = 2 * ca + (w >> 2);         // diag k-tile for this wave's chunk-a rows
  const int tgb = 2 * cb + (w >> 2);

  const bf16_t* qp = q + (size_t)b * 2048 * 3072 + h * 192;
  const bf16_t* kp = kbuf + (size_t)b * 2048 * 3072 + h * 192;
  const bf16_t* vp = vt + (size_t)bh * 192 * 2048;

  bf16x8 qf[2][6];
#pragma unroll
  for (int kd = 0; kd < 6; kd++) {
    qf[0][kd] = *(const bf16x8*)(qp + (size_t)(ra + l15) * 3072 + kd * 32 + l4 * 8);
    qf[1][kd] = *(const bf16x8*)(qp + (size_t)(rb + l15) * 3072 + kd * 32 + l4 * 8);
  }

  f32x4 o[2][12] = {};
  float mrow[2] = {-__builtin_inff(), -__builtin_inff()};
  float lrow[2] = {0.0f, 0.0f};

  const float scale = 0.07216878364870322f;  // 1/sqrt(192)
  const float THR = 7.0f;                    // defer-max threshold
  const int nkt = 2 * cb + 2;                // always even
  const int src0 = l15 + ((l4 & 1) << 5);
  const int src1 = src0 + 16;
  const bool hibank = (l4 & 2) != 0;

#define STAGE(SK, SV, KT)                                                           \
  {                                                                                 \
    const int k0s = (KT) * 64;                                                      \
    _Pragma("unroll")                                                               \
    for (int r = 0; r < 3; r++) {                                                   \
      int i = r * 512 + tid;                                                        \
      int row = i / 24, cc = i % 24;                                                \
      int g = cc - (row & 7) * 3;                                                   \
      if (g < 0) g += 24;                                                           \
      gload_lds16(kp + (size_t)(k0s + row) * 3072 + g * 8,                          \
                  (char*)&SK[0][0] + (size_t)(r * 512 + w * 64) * 16);              \
    }                                                                               \
    _Pragma("unroll")                                                               \
    for (int r = 0; r < 3; r++) {                                                   \
      int i = r * 512 + tid;                                                        \
      int d = i >> 3, cc = i & 7;                                                   \
      gload_lds16(vp + (size_t)d * 2048 + k0s + (cc ^ (d & 7)) * 8,                 \
                  (char*)&SV[0][0] + (size_t)(r * 512 + w * 64) * 16);              \
    }                                                                               \
  }

#define SOFTMAX_CHUNK(c, rbase, tg)                                                    \
    {                                                                                  \
      const bool diag = (kt == (tg));                                                  \
      _Pragma("unroll")                                                                \
      for (int nf = 0; nf < 4; nf++)                                                   \
        _Pragma("unroll")                                                              \
        for (int r = 0; r < 4; r++) {                                                  \
          float sv = s[c][nf][r] * scale;                                              \
          if (diag) {                                                                  \
            int ktok = k0 + nf * 16 + l4 * 4 + r;                                      \
            if (ktok > (rbase) + l15) sv = -__builtin_inff();                          \
          }                                                                            \
          s[c][nf][r] = sv;                                                            \
        }                                                                              \
      float m_in = s[c][0][0];                                                         \
      _Pragma("unroll")                                                                \
      for (int nf = 0; nf < 4; nf++)                                                   \
        _Pragma("unroll")                                                              \
        for (int r = 0; r < 4; r++)                                                    \
          if (nf | r) m_in = fmaxf(m_in, s[c][nf][r]);                                 \
      m_in = fmaxf(m_in, __shfl_xor(m_in, 16));                                        \
      m_in = fmaxf(m_in, __shfl_xor(m_in, 32));                                        \
      if (!__all(m_in - mrow[c] <= THR)) {                                             \
        float mn = fmaxf(mrow[c], m_in);                                               \
        float alpha = __expf(mrow[c] - mn);                                            \
        mrow[c] = mn;                                                                  \
        lrow[c] *= alpha;                                                              \
        f32x4 av;                                                                      \
        _Pragma("unroll")                                                              \
        for (int r = 0; r < 4; r++) av[r] = __shfl(alpha, l4 * 4 + r);                 \
        _Pragma("unroll")                                                              \
        for (int nf2 = 0; nf2 < 12; nf2++) o[c][nf2] *= av;                            \
      }                                                                                \
      float rs = 0.0f;                                                                 \
      _Pragma("unroll")                                                                \
      for (int nf = 0; nf < 4; nf++)                                                   \
        _Pragma("unroll")                                                              \
        for (int r = 0; r < 4; r++) {                                                  \
          float pv = __expf(s[c][nf][r] - mrow[c]);                                    \
          s[c][nf][r] = pv;                                                            \
          rs += pv;                                                                    \
        }                                                                              \
      rs += __shfl_xor(rs, 16);                                                        \
      rs += __shfl_xor(rs, 32);                                                        \
      lrow[c] += rs;                                                                   \
      uint32_t wq[8];                                                                  \
      _Pragma("unroll")                                                                \
      for (int nf = 0; nf < 4; nf++) {                                                 \
        wq[nf * 2 + 0] = pkbf(s[c][nf][0], s[c][nf][1]);                               \
        wq[nf * 2 + 1] = pkbf(s[c][nf][2], s[c][nf][3]);                               \
      }                                                                                \
      _Pragma("unroll")                                                                \
      for (int ks = 0; ks < 2; ks++) {                                                 \
        uint32_t A0 = __shfl(wq[(2 * ks) * 2 + 0], src0);                              \
        uint32_t A1 = __shfl(wq[(2 * ks) * 2 + 1], src0);                              \
        uint32_t B0 = __shfl(wq[(2 * ks + 1) * 2 + 0], src0);                          \
        uint32_t B1 = __shfl(wq[(2 * ks + 1) * 2 + 1], src0);                          \
        uint32_t C0w = __shfl(wq[(2 * ks) * 2 + 0], src1);                             \
        uint32_t C1w = __shfl(wq[(2 * ks) * 2 + 1], src1);                             \
        uint32_t D0 = __shfl(wq[(2 * ks + 1) * 2 + 0], src1);                          \
        uint32_t D1 = __shfl(wq[(2 * ks + 1) * 2 + 1], src1);                          \
        union { uint32_t u[4]; bf16x8 v; } fr;                                         \
        fr.u[0] = hibank ? B0 : A0;                                                    \
        fr.u[1] = hibank ? B1 : A1;                                                    \
        fr.u[2] = hibank ? D0 : C0w;                                                   \
        fr.u[3] = hibank ? D1 : C1w;                                                   \
        pa[c][ks] = fr.v;                                                              \
      }                                                                                \
    }

#define TILE_BODY(SK, SV, KT)                                                          \
  {                                                                                    \
    const int kt = (KT);                                                               \
    const int k0 = kt * 64;                                                            \
    const bool act_a = (kt <= tga);                                                    \
    const bool act_b = (kt <= tgb);                                                    \
    f32x4 s[2][4] = {};                                                                \
    __builtin_amdgcn_s_setprio(1);                                                     \
    _Pragma("unroll")                                                                  \
    for (int kd = 0; kd < 6; kd++) {                                                   \
      bf16x8 bk[4];                                                                    \
      _Pragma("unroll")                                                                \
      for (int nf = 0; nf < 4; nf++) {                                                 \
        int row = nf * 16 + l15;                                                       \
        int cl = kd * 4 + l4 + (row & 7) * 3;                                          \
        if (cl >= 24) cl -= 24;                                                        \
        bk[nf] = *(const bf16x8*)(&SK[row][cl * 8]);                                   \
      }                                                                                \
      if (act_b) {                                                                     \
        _Pragma("unroll")                                                              \
        for (int nf = 0; nf < 4; nf++)                                                 \
          s[1][nf] = MFMA16(bk[nf], qf[1][kd], s[1][nf]);                              \
      }                                                                                \
      if (act_a) {                                                                     \
        _Pragma("unroll")                                                              \
        for (int nf = 0; nf < 4; nf++)                                                 \
          s[0][nf] = MFMA16(bk[nf], qf[0][kd], s[0][nf]);                              \
      }                                                                                \
    }                                                                                  \
    __builtin_amdgcn_s_setprio(0);                                                     \
    bf16x8 pa[2][2] = {};                                                              \
    if (act_b) SOFTMAX_CHUNK(1, rb, tgb)                                               \
    if (act_a) SOFTMAX_CHUNK(0, ra, tga)                                               \
    __builtin_amdgcn_s_setprio(1);                                                     \
    _Pragma("unroll")                                                                  \
    for (int ks = 0; ks < 2; ks++) {                                                   \
      _Pragma("unroll")                                                                \
      for (int nf2 = 0; nf2 < 12; nf2++) {                                             \
        int d = nf2 * 16 + l15;                                                        \
        int cl = (ks * 4 + l4) ^ (d & 7);                                              \
        bf16x8 vb = *(const bf16x8*)(&SV[d][cl * 8]);                                  \
        if (act_b) o[1][nf2] = MFMA16(pa[1][ks], vb, o[1][nf2]);                       \
        if (act_a) o[0][nf2] = MFMA16(pa[0][ks], vb, o[0][nf2]);                       \
      }                                                                                \
    }                                                                                  \
    __builtin_amdgcn_s_setprio(0);                                                     \
  }

  STAGE(sK0, sV0, 0)
  __syncthreads();  // tile 0 ready

  for (int kt0 = 0; kt0 < nkt; kt0 += 2) {
    STAGE(sK1, sV1, kt0 + 1)
    TILE_BODY(sK0, sV0, kt0)
    __syncthreads();
    if (kt0 + 2 < nkt) STAGE(sK0, sV0, kt0 + 2)
    TILE_BODY(sK1, sV1, kt0 + 1)
    __syncthreads();
  }
#undef STAGE
#undef SOFTMAX_CHUNK
#undef TILE_BODY

  // epilogue: O/l -> ao (b*T+q, h*192+d), both chunks; l lives at lane l15=q
#pragma unroll
  for (int mf = 0; mf < 2; mf++) {
    const int rbase = (mf == 0) ? ra : rb;
#pragma unroll
    for (int r = 0; r < 4; r++) {
      float lv = __shfl(lrow[mf], l4 * 4 + r);
      float inv = 1.0f / lv;
      int qrow = rbase + l4 * 4 + r;
#pragma unroll
      for (int nf2 = 0; nf2 < 12; nf2++) {
        int d = nf2 * 16 + l15;
        ao[(size_t)(b * 2048 + qrow) * 3072 + h * 192 + d] = (bf16_t)(o[mf][nf2][r] * inv);
      }
    }
  }
}

// ----------------------------------------------------------------
extern "C" void kernel_launch(void* const* d_in, const int* in_sizes, int n_in,
                              void* d_out, int out_size, void* d_ws, size_t ws_size,
                              hipStream_t stream) {
  const float* x       = (const float*)d_in[0];
  const float* wq_down = (const float*)d_in[1];
  const float* wq_up   = (const float*)d_in[2];
  const float* wq_rope = (const float*)d_in[3];
  const float* wkv_down= (const float*)d_in[4];
  const float* wk_up   = (const float*)d_in[5];
  const float* wv_up   = (const float*)d_in[6];
  const float* wk_rope = (const float*)d_in[7];
  const float* wo      = (const float*)d_in[8];
  float* out = (float*)d_out;

  char* p = (char*)d_ws;
  auto take = [&](size_t elems) { bf16_t* r = (bf16_t*)p; p += elems * 2; return r; };
  bf16_t* xb    = take(4096ull * 2048);
  bf16_t* fw1   = take(3328ull * 2048);  // [wq_down(768) | wkv_down(512) | wq_rope(1024) | wk_rope(1024)]^T
  bf16_t* wqu_t = take(2048ull * 768);
  bf16_t* fw2   = take(5120ull * 512);   // [wk_up(2048) | wv_up(3072)]^T
  bf16_t* wo_t  = take(2048ull * 3072);
  bf16_t* qkvd  = take(4096ull * 1280);  // [q_down(768) | latent(512)]
  bf16_t* qbuf  = take(4096ull * 3072);
  bf16_t* kbuf  = take(4096ull * 3072);
  bf16_t* ao    = take(4096ull * 3072);
  bf16_t* vt    = take(4096ull * 3072);

  dim3 tb(32, 8);
  transpose_all<<<25088, tb, 0, stream>>>(
      wq_down, wkv_down, wq_rope, wk_rope, wq_up, wk_up, wv_up, wo,
      fw1, fw1 + 768ull * 2048, fw1 + 1280ull * 2048, fw1 + 2304ull * 2048,
      wqu_t, fw2, fw2 + 2048ull * 512, wo_t, x, xb);

  gemm128<4><<<dim3(26, 32), 512, 0, stream>>>(xb, 2048, fw1, qkvd, qbuf, kbuf, 2048, 0);
  gemm128<2><<<dim3(16, 32), 512, 0, stream>>>(qkvd, 1280, wqu_t, qbuf, nullptr, nullptr, 768, 0);
  gemm128<5><<<dim3(40, 32), 512, 0, stream>>>(qkvd + 768, 1280, fw2, kbuf, vt, nullptr, 512, 0);

  attn_kernel<<<256, 512, 0, stream>>>(qbuf, kbuf, vt, ao);

  gemm128<1><<<dim3(16, 32), 512, 0, stream>>>(ao, 3072, wo_t, out, nullptr, nullptr, 3072, 2048);
}